// Round 7
// baseline (63.529 us; speedup 1.0000x reference)
//
#include <hip/hip_runtime.h>

// Gaussian splatting preprocess: project 3D gaussians, 2D covariance, radii.
// Persistent grid-stride kernel, 4 gaussians/thread/iter, depth-1 register
// prefetch: loads for iteration i+1 issue before compute of iteration i, so
// every wave keeps ~10 dwordx4 in flight continuously (no phase-locked
// load-burst / compute-burst alternation).

typedef float v4f __attribute__((ext_vector_type(4)));

__device__ __forceinline__ float frcp(float x)  { return __builtin_amdgcn_rcpf(x); }
__device__ __forceinline__ float fsqrt_(float x){ return __builtin_amdgcn_sqrtf(x); }

__device__ __forceinline__ v4f vrcp(v4f a) {
    v4f r; r.x = frcp(a.x); r.y = frcp(a.y); r.z = frcp(a.z); r.w = frcp(a.w); return r;
}
__device__ __forceinline__ v4f vsqrt(v4f a) {
    v4f r; r.x = fsqrt_(a.x); r.y = fsqrt_(a.y); r.z = fsqrt_(a.z); r.w = fsqrt_(a.w); return r;
}
__device__ __forceinline__ v4f vmaxs(v4f a, float b) {
    v4f r; r.x = fmaxf(a.x,b); r.y = fmaxf(a.y,b); r.z = fmaxf(a.z,b); r.w = fmaxf(a.w,b); return r;
}
__device__ __forceinline__ v4f vclamp(v4f a, float lo, float hi) {
    v4f r;
    r.x = fminf(fmaxf(a.x, lo), hi);
    r.y = fminf(fmaxf(a.y, lo), hi);
    r.z = fminf(fmaxf(a.z, lo), hi);
    r.w = fminf(fmaxf(a.w, lo), hi);
    return r;
}
__device__ __forceinline__ v4f vceil(v4f a) {
    v4f r; r.x = ceilf(a.x); r.y = ceilf(a.y); r.z = ceilf(a.z); r.w = ceilf(a.w); return r;
}

struct Raw4 {               // raw loaded data for 4 gaussians (10 float4)
    float4 m0, m1, m2;      // 12 mean floats
    float4 s0, s1, s2;      // 12 scale floats
    float4 r0, r1, r2, r3;  // 16 quat floats
};

struct GaussChunk {
    v4f mx, my, mz;
    v4f qr, qx, qy, qz;
    v4f s0, s1, s2;
};

struct Cam {
    float vmr[16], pmr[16];
    float focal_x, focal_y, limx, limy, W, H, TX, TY, scmod;
};

__device__ __forceinline__ void load4(Raw4& g,
    const float4* __restrict__ m4, const float4* __restrict__ s4,
    const float4* __restrict__ r4, int t)
{
    const size_t t3 = (size_t)t * 3, t4 = (size_t)t * 4;
    g.m0 = m4[t3];   g.m1 = m4[t3+1]; g.m2 = m4[t3+2];
    g.s0 = s4[t3];   g.s1 = s4[t3+1]; g.s2 = s4[t3+2];
    g.r0 = r4[t4];   g.r1 = r4[t4+1]; g.r2 = r4[t4+2]; g.r3 = r4[t4+3];
}

__device__ __forceinline__ v4f gauss_radii(const GaussChunk& c, const Cam& K)
{
    const float* vmr = K.vmr;
    const float* pmr = K.pmr;

    const v4f pvx = c.mx*vmr[0] + c.my*vmr[4] + c.mz*vmr[8]  + vmr[12];
    const v4f pvy = c.mx*vmr[1] + c.my*vmr[5] + c.mz*vmr[9]  + vmr[13];
    const v4f tz  = c.mx*vmr[2] + c.my*vmr[6] + c.mz*vmr[10] + vmr[14];

    const v4f hx = c.mx*pmr[0] + c.my*pmr[4] + c.mz*pmr[8]  + pmr[12];
    const v4f hy = c.mx*pmr[1] + c.my*pmr[5] + c.mz*pmr[9]  + pmr[13];
    const v4f hw = c.mx*pmr[3] + c.my*pmr[7] + c.mz*pmr[11] + pmr[15];
    const v4f pw  = vrcp(hw + 1e-7f);
    const v4f ppx = hx * pw;
    const v4f ppy = hy * pw;

    const v4f itz = vrcp(tz);
    const v4f cx  = vclamp(pvx * itz, -K.limx, K.limx);
    const v4f cy  = vclamp(pvy * itz, -K.limy, K.limy);
    const v4f fxz = K.focal_x * itz;
    const v4f fyz = K.focal_y * itz;

    const v4f A0 = vmr[0] - vmr[2]*cx;
    const v4f A1 = vmr[4] - vmr[6]*cx;
    const v4f A2 = vmr[8] - vmr[10]*cx;
    const v4f B0 = vmr[1] - vmr[2]*cy;
    const v4f B1 = vmr[5] - vmr[6]*cy;
    const v4f B2 = vmr[9] - vmr[10]*cy;

    const v4f xx = c.qx*c.qx, yy = c.qy*c.qy, zz = c.qz*c.qz;
    const v4f xy = c.qx*c.qy, xz = c.qx*c.qz, yz = c.qy*c.qz;
    const v4f rx = c.qr*c.qx, ry = c.qr*c.qy, rz = c.qr*c.qz;
    const v4f R00 = 1.0f - 2.0f*(yy + zz);
    const v4f R01 = 2.0f*(xy - rz);
    const v4f R02 = 2.0f*(xz + ry);
    const v4f R10 = 2.0f*(xy + rz);
    const v4f R11 = 1.0f - 2.0f*(xx + zz);
    const v4f R12 = 2.0f*(yz - rx);
    const v4f R20 = 2.0f*(xz - ry);
    const v4f R21 = 2.0f*(yz + rx);
    const v4f R22 = 1.0f - 2.0f*(xx + yy);

    const v4f e0 = c.s0 * (R00*A0 + R01*A1 + R02*A2);
    const v4f e1 = c.s1 * (R10*A0 + R11*A1 + R12*A2);
    const v4f e2 = c.s2 * (R20*A0 + R21*A1 + R22*A2);
    const v4f f0 = c.s0 * (R00*B0 + R01*B1 + R02*B2);
    const v4f f1 = c.s1 * (R10*B0 + R11*B1 + R12*B2);
    const v4f f2 = c.s2 * (R20*B0 + R21*B1 + R22*B2);
    const v4f ee = e0*e0 + e1*e1 + e2*e2;
    const v4f ef = e0*f0 + e1*f1 + e2*f2;
    const v4f ff = f0*f0 + f1*f1 + f2*f2;

    const v4f cov_x = fxz*fxz*ee + 0.3f;
    const v4f cov_y = fxz*fyz*ef;
    const v4f cov_z = fyz*fyz*ff + 0.3f;
    const v4f det = cov_x*cov_z - cov_y*cov_y;
    const v4f mid = 0.5f*(cov_x + cov_z);
    const v4f lambda1 = mid + vsqrt(vmaxs(mid*mid - det, 0.1f));
    const v4f radius = vceil(3.0f * vsqrt(lambda1));

    const v4f pxs = ((ppx + 1.0f)*K.W - 1.0f)*0.5f;
    const v4f pys = ((ppy + 1.0f)*K.H - 1.0f)*0.5f;

    v4f res;
    #pragma unroll
    for (int u = 0; u < 4; ++u) {
        const float rad = radius[u];
        const float pxu = pxs[u], pyu = pys[u];
        const bool vx = ((pxu + rad + 15.0f) >= 16.0f) && ((pxu - rad) < K.TX);
        const bool vy = ((pyu + rad + 15.0f) >= 16.0f) && ((pyu - rad) < K.TY);
        const bool valid = (tz[u] > 0.2f) && (det[u] != 0.0f) && vx && vy;
        res[u] = valid ? rad : 0.0f;
    }
    return res;
}

__device__ __forceinline__ void process4(
    const Raw4& g, bool full, int t,
    const float* __restrict__ means, const float* __restrict__ scales,
    const float* __restrict__ rots, float* __restrict__ out,
    const Cam& K, int n)
{
    GaussChunk c;
    if (full) {
        c.mx = (v4f){g.m0.x, g.m0.w, g.m1.z, g.m2.y};
        c.my = (v4f){g.m0.y, g.m1.x, g.m1.w, g.m2.z};
        c.mz = (v4f){g.m0.z, g.m1.y, g.m2.x, g.m2.w};
        c.s0 = K.scmod * (v4f){g.s0.x, g.s0.w, g.s1.z, g.s2.y};
        c.s1 = K.scmod * (v4f){g.s0.y, g.s1.x, g.s1.w, g.s2.z};
        c.s2 = K.scmod * (v4f){g.s0.z, g.s1.y, g.s2.x, g.s2.w};
        c.qr = (v4f){g.r0.x, g.r1.x, g.r2.x, g.r3.x};
        c.qx = (v4f){g.r0.y, g.r1.y, g.r2.y, g.r3.y};
        c.qy = (v4f){g.r0.z, g.r1.z, g.r2.z, g.r3.z};
        c.qz = (v4f){g.r0.w, g.r1.w, g.r2.w, g.r3.w};
    } else {
        #pragma unroll
        for (int u = 0; u < 4; ++u) {
            const int gi = 4*t + u;
            float mv[3] = {0.f,0.f,0.f}, sv[3] = {0.f,0.f,0.f}, qv[4] = {1.f,0.f,0.f,0.f};
            if (gi < n) {
                mv[0]=means[3*(size_t)gi]; mv[1]=means[3*(size_t)gi+1]; mv[2]=means[3*(size_t)gi+2];
                sv[0]=scales[3*(size_t)gi]; sv[1]=scales[3*(size_t)gi+1]; sv[2]=scales[3*(size_t)gi+2];
                qv[0]=rots[4*(size_t)gi]; qv[1]=rots[4*(size_t)gi+1];
                qv[2]=rots[4*(size_t)gi+2]; qv[3]=rots[4*(size_t)gi+3];
            }
            c.mx[u]=mv[0]; c.my[u]=mv[1]; c.mz[u]=mv[2];
            c.s0[u]=K.scmod*sv[0]; c.s1[u]=K.scmod*sv[1]; c.s2[u]=K.scmod*sv[2];
            c.qr[u]=qv[0]; c.qx[u]=qv[1]; c.qy[u]=qv[2]; c.qz[u]=qv[3];
        }
    }
    const v4f res = gauss_radii(c, K);
    if (full) {
        __builtin_nontemporal_store(res, (v4f*)out + t);
    } else {
        #pragma unroll
        for (int u = 0; u < 4; ++u)
            if (4*t + u < n) out[4*t + u] = res[u];
    }
}

__global__ __launch_bounds__(256) void gauss_pre_kernel(
    const float* __restrict__ means,   // N*3
    const float* __restrict__ scales,  // N*3
    const float* __restrict__ rots,    // N*4
    const float* __restrict__ vm,      // 16
    const float* __restrict__ pm,      // 16
    const float* __restrict__ s_tanfovx,
    const float* __restrict__ s_tanfovy,
    const float* __restrict__ s_scmod,
    const int*   __restrict__ s_ih,
    const int*   __restrict__ s_iw,
    float* __restrict__ out,           // N
    int n)
{
    const int n4 = (n + 3) >> 2;
    int t = blockIdx.x * blockDim.x + threadIdx.x;
    if (t >= n4) return;
    const int T = gridDim.x * blockDim.x;

    Cam K;
    K.scmod = s_scmod[0];
    const float tanfovx = s_tanfovx[0];
    const float tanfovy = s_tanfovy[0];
    K.H = (float)s_ih[0];
    K.W = (float)s_iw[0];
    K.focal_x = K.W * 0.5f * frcp(tanfovx);
    K.focal_y = K.H * 0.5f * frcp(tanfovy);
    K.limx = 1.3f * tanfovx;
    K.limy = 1.3f * tanfovy;
    K.TX = 16.0f * ceilf((K.W + 15.0f) * 0.0625f);
    K.TY = 16.0f * ceilf((K.H + 15.0f) * 0.0625f);
    #pragma unroll
    for (int i = 0; i < 4; ++i) {
        float4 a = ((const float4*)vm)[i];
        K.vmr[4*i+0]=a.x; K.vmr[4*i+1]=a.y; K.vmr[4*i+2]=a.z; K.vmr[4*i+3]=a.w;
        float4 b = ((const float4*)pm)[i];
        K.pmr[4*i+0]=b.x; K.pmr[4*i+1]=b.y; K.pmr[4*i+2]=b.z; K.pmr[4*i+3]=b.w;
    }

    const float4* m4 = (const float4*)means;
    const float4* s4 = (const float4*)scales;
    const float4* r4 = (const float4*)rots;

    Raw4 bufA, bufB;
    bool fullA = (4*(size_t)t + 3 < (size_t)n);
    if (fullA) load4(bufA, m4, s4, r4, t);

    for (;;) {
        // ---- phase A: current = t in bufA; prefetch t+T into bufB ----
        const int tB = t + T;
        const bool hasB = tB < n4;
        const bool fullB = hasB && (4*(size_t)tB + 3 < (size_t)n);
        if (fullB) load4(bufB, m4, s4, r4, tB);
        process4(bufA, fullA, t, means, scales, rots, out, K, n);
        if (!hasB) break;

        // ---- phase B: current = tB in bufB; prefetch tB+T into bufA ----
        const int tA = tB + T;
        const bool hasA = tA < n4;
        const bool fullA2 = hasA && (4*(size_t)tA + 3 < (size_t)n);
        if (fullA2) load4(bufA, m4, s4, r4, tA);
        process4(bufB, fullB, tB, means, scales, rots, out, K, n);
        if (!hasA) break;

        t = tA;
        fullA = fullA2;
    }
}

extern "C" void kernel_launch(void* const* d_in, const int* in_sizes, int n_in,
                              void* d_out, int out_size, void* d_ws, size_t ws_size,
                              hipStream_t stream) {
    const float* means  = (const float*)d_in[0];
    const float* scales = (const float*)d_in[1];
    const float* rots   = (const float*)d_in[2];
    const float* vm     = (const float*)d_in[3];
    const float* pm     = (const float*)d_in[4];
    const float* tfx    = (const float*)d_in[5];
    const float* tfy    = (const float*)d_in[6];
    const float* scm    = (const float*)d_in[7];
    const int*   ih     = (const int*)d_in[8];
    const int*   iw     = (const int*)d_in[9];
    float* out = (float*)d_out;

    const int n = in_sizes[0] / 3;           // N gaussians
    const int n4 = (n + 3) / 4;
    int nblocks = 1024;                      // persistent: ~3.8 iters/thread
    const int maxb = (n4 + 255) / 256;
    if (nblocks > maxb) nblocks = maxb;
    dim3 block(256);
    dim3 grid(nblocks);
    hipLaunchKernelGGL(gauss_pre_kernel, grid, block, 0, stream,
                       means, scales, rots, vm, pm, tfx, tfy, scm, ih, iw, out, n);
}

// Round 8
// 31.659 us; speedup vs baseline: 2.0067x; 2.0067x over previous
//
#include <hip/hip_runtime.h>

// Gaussian splatting preprocess: project 3D gaussians, 2D covariance, radii.
// One thread processes 8 gaussians as two 4-wide packed-f32 chunks.
// (R5 configuration — best measured: 31.7 us, 5.55 TB/s consumed BW.)

typedef float v4f __attribute__((ext_vector_type(4)));

__device__ __forceinline__ float frcp(float x)  { return __builtin_amdgcn_rcpf(x); }
__device__ __forceinline__ float fsqrt_(float x){ return __builtin_amdgcn_sqrtf(x); }

__device__ __forceinline__ v4f vrcp(v4f a) {
    v4f r; r.x = frcp(a.x); r.y = frcp(a.y); r.z = frcp(a.z); r.w = frcp(a.w); return r;
}
__device__ __forceinline__ v4f vsqrt(v4f a) {
    v4f r; r.x = fsqrt_(a.x); r.y = fsqrt_(a.y); r.z = fsqrt_(a.z); r.w = fsqrt_(a.w); return r;
}
__device__ __forceinline__ v4f vmaxs(v4f a, float b) {
    v4f r; r.x = fmaxf(a.x,b); r.y = fmaxf(a.y,b); r.z = fmaxf(a.z,b); r.w = fmaxf(a.w,b); return r;
}
__device__ __forceinline__ v4f vclamp(v4f a, float lo, float hi) {
    v4f r;
    r.x = fminf(fmaxf(a.x, lo), hi);
    r.y = fminf(fmaxf(a.y, lo), hi);
    r.z = fminf(fmaxf(a.z, lo), hi);
    r.w = fminf(fmaxf(a.w, lo), hi);
    return r;
}
__device__ __forceinline__ v4f vceil(v4f a) {
    v4f r; r.x = ceilf(a.x); r.y = ceilf(a.y); r.z = ceilf(a.z); r.w = ceilf(a.w); return r;
}

struct GaussChunk {
    v4f mx, my, mz;      // means (SoA over 4 gaussians)
    v4f qr, qx, qy, qz;  // quaternion
    v4f s0, s1, s2;      // pre-scaled scales
};

__device__ __forceinline__ v4f gauss_radii(
    const GaussChunk& c,
    const float* __restrict__ vmr, const float* __restrict__ pmr,
    float focal_x, float focal_y, float limx, float limy,
    float W, float H, float TX, float TY)
{
    // p_view
    const v4f pvx = c.mx*vmr[0] + c.my*vmr[4] + c.mz*vmr[8]  + vmr[12];
    const v4f pvy = c.mx*vmr[1] + c.my*vmr[5] + c.mz*vmr[9]  + vmr[13];
    const v4f tz  = c.mx*vmr[2] + c.my*vmr[6] + c.mz*vmr[10] + vmr[14];

    // p_hom (x, y, w)
    const v4f hx = c.mx*pmr[0] + c.my*pmr[4] + c.mz*pmr[8]  + pmr[12];
    const v4f hy = c.mx*pmr[1] + c.my*pmr[5] + c.mz*pmr[9]  + pmr[13];
    const v4f hw = c.mx*pmr[3] + c.my*pmr[7] + c.mz*pmr[11] + pmr[15];
    const v4f pw  = vrcp(hw + 1e-7f);
    const v4f ppx = hx * pw;
    const v4f ppy = hy * pw;

    // clipped screen derivatives
    const v4f itz = vrcp(tz);
    const v4f cx  = vclamp(pvx * itz, -limx, limx);
    const v4f cy  = vclamp(pvy * itz, -limy, limy);
    const v4f fxz = focal_x * itz;
    const v4f fyz = focal_y * itz;

    // T2[:,0] = fxz*A, T2[:,1] = fyz*B
    const v4f A0 = vmr[0] - vmr[2]*cx;
    const v4f A1 = vmr[4] - vmr[6]*cx;
    const v4f A2 = vmr[8] - vmr[10]*cx;
    const v4f B0 = vmr[1] - vmr[2]*cy;
    const v4f B1 = vmr[5] - vmr[6]*cy;
    const v4f B2 = vmr[9] - vmr[10]*cy;

    // quaternion -> R rows
    const v4f xx = c.qx*c.qx, yy = c.qy*c.qy, zz = c.qz*c.qz;
    const v4f xy = c.qx*c.qy, xz = c.qx*c.qz, yz = c.qy*c.qz;
    const v4f rx = c.qr*c.qx, ry = c.qr*c.qy, rz = c.qr*c.qz;
    const v4f R00 = 1.0f - 2.0f*(yy + zz);
    const v4f R01 = 2.0f*(xy - rz);
    const v4f R02 = 2.0f*(xz + ry);
    const v4f R10 = 2.0f*(xy + rz);
    const v4f R11 = 1.0f - 2.0f*(xx + zz);
    const v4f R12 = 2.0f*(yz - rx);
    const v4f R20 = 2.0f*(xz - ry);
    const v4f R21 = 2.0f*(yz + rx);
    const v4f R22 = 1.0f - 2.0f*(xx + yy);

    // cov2 = (M T2)^T (M T2), M[k][:] = s_k R[k][:]
    const v4f e0 = c.s0 * (R00*A0 + R01*A1 + R02*A2);
    const v4f e1 = c.s1 * (R10*A0 + R11*A1 + R12*A2);
    const v4f e2 = c.s2 * (R20*A0 + R21*A1 + R22*A2);
    const v4f f0 = c.s0 * (R00*B0 + R01*B1 + R02*B2);
    const v4f f1 = c.s1 * (R10*B0 + R11*B1 + R12*B2);
    const v4f f2 = c.s2 * (R20*B0 + R21*B1 + R22*B2);
    const v4f ee = e0*e0 + e1*e1 + e2*e2;
    const v4f ef = e0*f0 + e1*f1 + e2*f2;
    const v4f ff = f0*f0 + f1*f1 + f2*f2;

    const v4f cov_x = fxz*fxz*ee + 0.3f;
    const v4f cov_y = fxz*fyz*ef;
    const v4f cov_z = fyz*fyz*ff + 0.3f;
    const v4f det = cov_x*cov_z - cov_y*cov_y;
    const v4f mid = 0.5f*(cov_x + cov_z);
    const v4f lambda1 = mid + vsqrt(vmaxs(mid*mid - det, 0.1f));
    const v4f radius = vceil(3.0f * vsqrt(lambda1));

    const v4f pxs = ((ppx + 1.0f)*W - 1.0f)*0.5f;
    const v4f pys = ((ppy + 1.0f)*H - 1.0f)*0.5f;

    // analytic area!=0 test (exact equivalent of the floor/clamp formulation)
    v4f res;
    #pragma unroll
    for (int u = 0; u < 4; ++u) {
        const float rad = radius[u];
        const float pxu = pxs[u], pyu = pys[u];
        const bool vx = ((pxu + rad + 15.0f) >= 16.0f) && ((pxu - rad) < TX);
        const bool vy = ((pyu + rad + 15.0f) >= 16.0f) && ((pyu - rad) < TY);
        const bool valid = (tz[u] > 0.2f) && (det[u] != 0.0f) && vx && vy;
        res[u] = valid ? rad : 0.0f;
    }
    return res;
}

__global__ __launch_bounds__(256) void gauss_pre_kernel(
    const float* __restrict__ means,   // N*3
    const float* __restrict__ scales,  // N*3
    const float* __restrict__ rots,    // N*4
    const float* __restrict__ vm,      // 16 (row-major 4x4)
    const float* __restrict__ pm,      // 16
    const float* __restrict__ s_tanfovx,
    const float* __restrict__ s_tanfovy,
    const float* __restrict__ s_scmod,
    const int*   __restrict__ s_ih,
    const int*   __restrict__ s_iw,
    float* __restrict__ out,           // N
    int n)
{
    const int t  = blockIdx.x * blockDim.x + threadIdx.x;
    const int g0 = t * 8;
    if (g0 >= n) return;

    const float tanfovx = s_tanfovx[0];
    const float tanfovy = s_tanfovy[0];
    const float scmod   = s_scmod[0];
    const float H = (float)s_ih[0];
    const float W = (float)s_iw[0];
    const float focal_x = W * 0.5f * frcp(tanfovx);
    const float focal_y = H * 0.5f * frcp(tanfovy);
    const float limx = 1.3f * tanfovx;
    const float limy = 1.3f * tanfovy;
    const float gx = (W + 15.0f) * 0.0625f;   // /16 exact
    const float gy = (H + 15.0f) * 0.0625f;
    const float TX = 16.0f * ceilf(gx);
    const float TY = 16.0f * ceilf(gy);

    // uniform matrices (uniform address -> scalar loads)
    float vmr[16], pmr[16];
    #pragma unroll
    for (int i = 0; i < 4; ++i) {
        float4 a = ((const float4*)vm)[i];
        vmr[4*i+0] = a.x; vmr[4*i+1] = a.y; vmr[4*i+2] = a.z; vmr[4*i+3] = a.w;
        float4 b = ((const float4*)pm)[i];
        pmr[4*i+0] = b.x; pmr[4*i+1] = b.y; pmr[4*i+2] = b.z; pmr[4*i+3] = b.w;
    }

    GaussChunk ch[2];
    const bool full = (g0 + 7 < n);
    if (full) {
        // 20 independent dwordx4 loads — all issue before first use
        const float4* m4 = (const float4*)means  + (size_t)t * 6;
        const float4* s4 = (const float4*)scales + (size_t)t * 6;
        const float4* r4 = (const float4*)rots   + (size_t)t * 8;
        const float4 m0 = m4[0], m1 = m4[1], m2 = m4[2], m3 = m4[3], m5 = m4[4], m6 = m4[5];
        const float4 sA = s4[0], sB = s4[1], sC = s4[2], sD = s4[3], sE = s4[4], sF = s4[5];
        const float4 r0 = r4[0], r1 = r4[1], r2 = r4[2], r3 = r4[3];
        const float4 r5 = r4[4], r6 = r4[5], r7 = r4[6], r8 = r4[7];

        ch[0].mx = (v4f){m0.x, m0.w, m1.z, m2.y};
        ch[0].my = (v4f){m0.y, m1.x, m1.w, m2.z};
        ch[0].mz = (v4f){m0.z, m1.y, m2.x, m2.w};
        ch[1].mx = (v4f){m3.x, m3.w, m5.z, m6.y};
        ch[1].my = (v4f){m3.y, m5.x, m5.w, m6.z};
        ch[1].mz = (v4f){m3.z, m5.y, m6.x, m6.w};

        ch[0].s0 = scmod * (v4f){sA.x, sA.w, sB.z, sC.y};
        ch[0].s1 = scmod * (v4f){sA.y, sB.x, sB.w, sC.z};
        ch[0].s2 = scmod * (v4f){sA.z, sB.y, sC.x, sC.w};
        ch[1].s0 = scmod * (v4f){sD.x, sD.w, sE.z, sF.y};
        ch[1].s1 = scmod * (v4f){sD.y, sE.x, sE.w, sF.z};
        ch[1].s2 = scmod * (v4f){sD.z, sE.y, sF.x, sF.w};

        ch[0].qr = (v4f){r0.x, r1.x, r2.x, r3.x};
        ch[0].qx = (v4f){r0.y, r1.y, r2.y, r3.y};
        ch[0].qy = (v4f){r0.z, r1.z, r2.z, r3.z};
        ch[0].qz = (v4f){r0.w, r1.w, r2.w, r3.w};
        ch[1].qr = (v4f){r5.x, r6.x, r7.x, r8.x};
        ch[1].qx = (v4f){r5.y, r6.y, r7.y, r8.y};
        ch[1].qy = (v4f){r5.z, r6.z, r7.z, r8.z};
        ch[1].qz = (v4f){r5.w, r6.w, r7.w, r8.w};
    } else {
        #pragma unroll
        for (int h = 0; h < 2; ++h) {
            #pragma unroll
            for (int u = 0; u < 4; ++u) {
                const int g = g0 + h*4 + u;
                float mv[3] = {0.f, 0.f, 0.f};
                float sv[3] = {0.f, 0.f, 0.f};
                float qv[4] = {1.f, 0.f, 0.f, 0.f};
                if (g < n) {
                    mv[0] = means[3*(size_t)g+0];
                    mv[1] = means[3*(size_t)g+1];
                    mv[2] = means[3*(size_t)g+2];
                    sv[0] = scales[3*(size_t)g+0];
                    sv[1] = scales[3*(size_t)g+1];
                    sv[2] = scales[3*(size_t)g+2];
                    qv[0] = rots[4*(size_t)g+0];
                    qv[1] = rots[4*(size_t)g+1];
                    qv[2] = rots[4*(size_t)g+2];
                    qv[3] = rots[4*(size_t)g+3];
                }
                ch[h].mx[u] = mv[0]; ch[h].my[u] = mv[1]; ch[h].mz[u] = mv[2];
                ch[h].s0[u] = scmod*sv[0]; ch[h].s1[u] = scmod*sv[1]; ch[h].s2[u] = scmod*sv[2];
                ch[h].qr[u] = qv[0]; ch[h].qx[u] = qv[1];
                ch[h].qy[u] = qv[2]; ch[h].qz[u] = qv[3];
            }
        }
    }

    v4f res0 = gauss_radii(ch[0], vmr, pmr, focal_x, focal_y, limx, limy, W, H, TX, TY);
    v4f res1 = gauss_radii(ch[1], vmr, pmr, focal_x, focal_y, limx, limy, W, H, TX, TY);

    if (full) {
        __builtin_nontemporal_store(res0, (v4f*)out + 2*(size_t)t);
        __builtin_nontemporal_store(res1, (v4f*)out + 2*(size_t)t + 1);
    } else {
        #pragma unroll
        for (int u = 0; u < 4; ++u) {
            if (g0 + u < n) out[g0 + u] = res0[u];
        }
        #pragma unroll
        for (int u = 0; u < 4; ++u) {
            if (g0 + 4 + u < n) out[g0 + 4 + u] = res1[u];
        }
    }
}

extern "C" void kernel_launch(void* const* d_in, const int* in_sizes, int n_in,
                              void* d_out, int out_size, void* d_ws, size_t ws_size,
                              hipStream_t stream) {
    const float* means  = (const float*)d_in[0];
    const float* scales = (const float*)d_in[1];
    const float* rots   = (const float*)d_in[2];
    const float* vm     = (const float*)d_in[3];
    const float* pm     = (const float*)d_in[4];
    const float* tfx    = (const float*)d_in[5];
    const float* tfy    = (const float*)d_in[6];
    const float* scm    = (const float*)d_in[7];
    const int*   ih     = (const int*)d_in[8];
    const int*   iw     = (const int*)d_in[9];
    float* out = (float*)d_out;

    const int n  = in_sizes[0] / 3;          // N gaussians
    const int n8 = (n + 7) / 8;              // threads (8 gaussians each)
    dim3 block(256);
    dim3 grid((n8 + 255) / 256);
    hipLaunchKernelGGL(gauss_pre_kernel, grid, block, 0, stream,
                       means, scales, rots, vm, pm, tfx, tfy, scm, ih, iw, out, n);
}